// Round 2
// baseline (220.117 us; speedup 1.0000x reference)
//
#include <hip/hip_runtime.h>
#include <stdint.h>

#define N_NODES 4096
#define F_DIM   256
#define BATCH   8

typedef __attribute__((ext_vector_type(8))) __bf16 bf16x8;
typedef __attribute__((ext_vector_type(4))) float  f32x4;
typedef __attribute__((ext_vector_type(8))) unsigned short u16x8;

typedef const __attribute__((address_space(1))) void* gas1_t;
typedef __attribute__((address_space(3))) void*       las3_t;

__device__ __forceinline__ void stage16(const void* g, void* l) {
  __builtin_amdgcn_global_load_lds((gas1_t)g, (las3_t)l, 16, 0, 0);
}

__device__ __forceinline__ unsigned short f2bf(float f) {
  union { float f; uint32_t u; } v; v.f = f;
  uint32_t u = v.u;
  return (unsigned short)((u + 0x7FFFu + ((u >> 16) & 1u)) >> 16); // RTNE
}
__device__ __forceinline__ float bf2f(unsigned short u) {
  union { uint32_t u; float f; } v; v.u = ((uint32_t)u) << 16;
  return v.f;
}

// ---------------- k_pre: fused H/W bf16 casts + symmetrize+degree (vectorized) ----
// 64x64 tile per block (bj>=bi). float4 A loads; second tile stored pre-transposed
// (stride 67 -> ~2-way LDS write conflicts); u16x8 Sb stores; row partial sums
// in-register; one columnar reduction pass (stride 68 -> conflict-free).
__global__ __launch_bounds__(256) void k_pre(const float* __restrict__ A,
                                             unsigned short* __restrict__ Sb,
                                             float* __restrict__ D,
                                             const float4* __restrict__ H4,
                                             ushort4* __restrict__ Hb4,
                                             const float* __restrict__ W,
                                             unsigned short* __restrict__ Wt) {
  int t = threadIdx.x;
  int bid = blockIdx.y * 64 + blockIdx.x;
  {
    int i = bid * 512 + t;
    float4 v = H4[i];
    ushort4 o; o.x = f2bf(v.x); o.y = f2bf(v.y); o.z = f2bf(v.z); o.w = f2bf(v.w);
    Hb4[i] = o;
    i += 256;
    v = H4[i];
    o.x = f2bf(v.x); o.y = f2bf(v.y); o.z = f2bf(v.z); o.w = f2bf(v.w);
    Hb4[i] = o;
  }
  if (bid < 256) Wt[t * 256 + bid] = f2bf(W[bid * 256 + t]);

  int bi = blockIdx.y, bj = blockIdx.x;
  if (bj < bi) return;

  __shared__ __align__(16) float T1[64][68];  // A(bi,bj) tile, then v
  __shared__ float Tt[64][67];                // A(bj,bi) tile, pre-transposed
  __shared__ float Pr4[64][4];
  __shared__ float Pc[4][64];
  int i0 = bi * 64, j0 = bj * 64;

  // load phase: vector loads; Tt stored transposed at write time
#pragma unroll
  for (int it = 0; it < 4; ++it) {
    int idx = it * 256 + t;
    int r = idx >> 4, c4 = (idx & 15) * 4;
    float4 v1 = *(const float4*)(A + (size_t)(i0 + r) * N_NODES + j0 + c4);
    *(float4*)&T1[r][c4] = v1;
    float4 v2 = *(const float4*)(A + (size_t)(j0 + r) * N_NODES + i0 + c4);
    Tt[c4 + 0][r] = v2.x; Tt[c4 + 1][r] = v2.y; Tt[c4 + 2][r] = v2.z; Tt[c4 + 3][r] = v2.w;
  }
  __syncthreads();

  // compute: each thread owns row r, cols {cb..cb+7} u {cb+32..cb+39}
  {
    int r = t >> 2, cb = (t & 3) * 8;
    float rowpart = 0.f;
#pragma unroll
    for (int g = 0; g < 2; ++g) {
      int c0 = cb + g * 32;
      u16x8 u;
      float vv[8];
#pragma unroll
      for (int i = 0; i < 8; ++i) {
        float v = 0.5f * (T1[r][c0 + i] + Tt[r][c0 + i]);
        v = v > 0.f ? v : 0.f;
        vv[i] = v;
        rowpart += v;
        u[i] = f2bf(v);
      }
      *(u16x8*)&Sb[(size_t)(i0 + r) * N_NODES + j0 + c0] = u;
      *(float4*)&T1[r][c0]     = make_float4(vv[0], vv[1], vv[2], vv[3]);
      *(float4*)&T1[r][c0 + 4] = make_float4(vv[4], vv[5], vv[6], vv[7]);
    }
    Pr4[r][t & 3] = rowpart;
  }
  __syncthreads();

  // column sums (v now in T1); stride 68 -> conflict-free columnar reads
  {
    int c = t & 63, seg = t >> 6;
    float s = 0.f;
#pragma unroll
    for (int i = 0; i < 16; ++i) s += T1[seg * 16 + i][c];
    Pc[seg][c] = s;
  }
  __syncthreads();

  if (t < 64) {
    atomicAdd(&D[i0 + t], Pr4[t][0] + Pr4[t][1] + Pr4[t][2] + Pr4[t][3]);
  } else if (t < 128 && bi != bj) {
    int c = t - 64;
    atomicAdd(&D[j0 + c], Pc[0][c] + Pc[1][c] + Pc[2][c] + Pc[3][c]);
  }

  if (bi != bj) {
    // transposed Sb write: 8 consecutive lanes cover one output row (128 B)
#pragma unroll
    for (int it = 0; it < 2; ++it) {
      int u = it * 256 + t;
      int co = u >> 3, rc = (u & 7) * 8;
      u16x8 o;
#pragma unroll
      for (int i = 0; i < 8; ++i) o[i] = f2bf(T1[rc + i][co]);
      *(u16x8*)&Sb[(size_t)(j0 + co) * N_NODES + i0 + rc] = o;
    }
  }
}

__global__ void k_dinv(const float* __restrict__ D, float* __restrict__ dinv) {
  int i = blockIdx.x * blockDim.x + threadIdx.x;
  if (i < N_NODES) {
    float d = D[i];
    dinv[i] = d > 0.f ? 1.0f / sqrtf(d) : 0.f;
  }
}

// ---------------- GEMM1 (single-shot): stage A-tile[128x256] + W-half[128x256]
// into LDS once (swizzled source, rule #21), one barrier, all K=256 in MFMA with
// no further staging barriers. Epilogue: HWb + LDS-transpose -> Gt (dinv-scaled).
__global__ __launch_bounds__(512) void k_gemm1(const unsigned short* __restrict__ Hb,
                                               const unsigned short* __restrict__ Wt,
                                               const float* __restrict__ dinv,
                                               unsigned short* __restrict__ HWb,
                                               unsigned short* __restrict__ Gt) {
  __shared__ __align__(16) unsigned short L[65536];  // As[128*256] | Ws[128*256], 128 KB
  int t = threadIdx.x;
  int lane = t & 63, r16 = lane & 15, q = lane >> 4;
  int wave = t >> 6;
  int wm = wave >> 2, wn = wave & 3;   // 2 x 4 wave grid, wave tile 64x32
  int nh = blockIdx.x;                 // N-half
  int m0 = blockIdx.y * 128;
  int n0 = nh * 128;

  // stage: 8 iters x 2 loads/thread; rows of 512 B = 32 chunks of 16 B;
  // source chunk = lds chunk ^ (row&7) (XOR involution, linear LDS dest)
#pragma unroll
  for (int i = 0; i < 8; ++i) {
    int s = i * 512 + t;
    int row = s >> 5, cl = s & 31;
    int cs = cl ^ (row & 7);
    uint32_t dst = (uint32_t)(i * 512 + (t & ~63)) * 16;
    stage16(Hb + (size_t)(m0 + row) * 256 + cs * 8, (char*)L + dst);
    stage16(Wt + (size_t)(n0 + row) * 256 + cs * 8, (char*)L + 65536 + dst);
  }
  __syncthreads();

  f32x4 acc[4][2];
#pragma unroll
  for (int i = 0; i < 4; ++i)
#pragma unroll
    for (int j = 0; j < 2; ++j) acc[i][j] = f32x4{0.f, 0.f, 0.f, 0.f};

#pragma unroll
  for (int ks = 0; ks < 8; ++ks) {
    bf16x8 a[4], b[2];
#pragma unroll
    for (int mi = 0; mi < 4; ++mi) {
      int ra = wm * 64 + mi * 16 + r16;
      a[mi] = *(const bf16x8*)((const char*)L + ra * 512 + (((ks * 4 + q) ^ (ra & 7)) << 4));
    }
#pragma unroll
    for (int ni = 0; ni < 2; ++ni) {
      int rb = wn * 32 + ni * 16 + r16;
      b[ni] = *(const bf16x8*)((const char*)L + 65536 + rb * 512 + (((ks * 4 + q) ^ (rb & 7)) << 4));
    }
#pragma unroll
    for (int mi = 0; mi < 4; ++mi)
#pragma unroll
      for (int ni = 0; ni < 2; ++ni)
        acc[mi][ni] = __builtin_amdgcn_mfma_f32_16x16x32_bf16(a[mi], b[ni], acc[mi][ni], 0, 0, 0);
  }
  __syncthreads();  // all waves done reading As before T overwrites it

  // epilogue 1: HWb stores + transpose into T (aliases As region)
  unsigned short (*T)[136] = (unsigned short (*)[136])L;  // 128x136 = 34816 B < 64 KB
#pragma unroll
  for (int mi = 0; mi < 4; ++mi) {
    int rowl = wm * 64 + mi * 16 + q * 4;
#pragma unroll
    for (int ni = 0; ni < 2; ++ni) {
      int coll = wn * 32 + ni * 16 + r16;
#pragma unroll
      for (int rr = 0; rr < 4; ++rr) {
        unsigned short h = f2bf(acc[mi][ni][rr]);
        HWb[(size_t)(m0 + rowl + rr) * F_DIM + (n0 + coll)] = h;
        T[coll][rowl + rr] = h;
      }
    }
  }
  __syncthreads();

  // epilogue 2: Gt[(b*256+o)][n] = dinv[n] * HW[.][o], vectorized u16x8
  int b = m0 >> 12, nb = m0 & 4095;
#pragma unroll
  for (int i = 0; i < 4; ++i) {
    int u = i * 512 + t;
    int co = u >> 4, cs = (u & 15) * 8;
    u16x8 v = *(const u16x8*)&T[co][cs];
    float4 d0 = *(const float4*)&dinv[nb + cs];
    float4 d1 = *(const float4*)&dinv[nb + cs + 4];
    u16x8 w;
    w[0] = f2bf(bf2f(v[0]) * d0.x);
    w[1] = f2bf(bf2f(v[1]) * d0.y);
    w[2] = f2bf(bf2f(v[2]) * d0.z);
    w[3] = f2bf(bf2f(v[3]) * d0.w);
    w[4] = f2bf(bf2f(v[4]) * d1.x);
    w[5] = f2bf(bf2f(v[5]) * d1.y);
    w[6] = f2bf(bf2f(v[6]) * d1.z);
    w[7] = f2bf(bf2f(v[7]) * d1.w);
    *(u16x8*)&Gt[(size_t)(b * 256 + n0 + co) * N_NODES + nb + cs] = w;
  }
}

// ---------------- GEMM2: triple-buffered counted-vmcnt pipeline (unchanged) -----
#define LDSB 49152  // bytes per buffer: A 32768 + B 16384

__global__ __launch_bounds__(512, 2) void k_gemm2(const unsigned short* __restrict__ Sb,
                                                  const unsigned short* __restrict__ Gt,
                                                  const unsigned short* __restrict__ HWb,
                                                  const float* __restrict__ dinv,
                                                  float* __restrict__ Out) {
  __shared__ __align__(16) unsigned short LDS[3 * 24576];  // 147456 B
  const int NT = N_NODES / 64;  // 64 K-tiles
  int t = threadIdx.x;
  int lane = t & 63, r16 = lane & 15, q = lane >> 4;
  int wave = t >> 6;
  int wm = wave >> 1, wn = wave & 1;

  int bid = blockIdx.x;
  int xcd = bid & 7, j = bid >> 3;
  int mt = (xcd >> 1) * 4 + (j & 3);
  int nt = (xcd & 1) * 8 + (j >> 2);
  int m0 = mt * 256, n0 = nt * 128;

  const char* aSrc[4]; const char* bSrc[2];
  uint32_t aDst[4], bDst[2];
#pragma unroll
  for (int i = 0; i < 4; ++i) {
    int slot = i * 512 + t;
    int row = slot >> 3;
    int c = (slot & 7) ^ (row & 7);
    aSrc[i] = (const char*)Sb + (size_t)(m0 + row) * 8192 + c * 16;
    aDst[i] = (uint32_t)(i * 512 + (t & ~63)) * 16;
  }
#pragma unroll
  for (int i = 0; i < 2; ++i) {
    int slot = i * 512 + t;
    int row = slot >> 3;
    int c = (slot & 7) ^ (row & 7);
    bSrc[i] = (const char*)Gt + (size_t)(n0 + row) * 8192 + c * 16;
    bDst[i] = 32768u + (uint32_t)(i * 512 + (t & ~63)) * 16;
  }

  int aoff[4][2], boff[4][2];
#pragma unroll
  for (int mi = 0; mi < 4; ++mi) {
    int ra = wm * 64 + mi * 16 + r16;
#pragma unroll
    for (int ks = 0; ks < 2; ++ks)
      aoff[mi][ks] = ra * 128 + (((ks * 4 + q) ^ (ra & 7)) << 4);
  }
#pragma unroll
  for (int ni = 0; ni < 4; ++ni) {
    int rb = wn * 64 + ni * 16 + r16;
#pragma unroll
    for (int ks = 0; ks < 2; ++ks)
      boff[ni][ks] = 32768 + rb * 128 + (((ks * 4 + q) ^ (rb & 7)) << 4);
  }

  f32x4 acc[4][4];
#pragma unroll
  for (int i = 0; i < 4; ++i)
#pragma unroll
    for (int jj = 0; jj < 4; ++jj) acc[i][jj] = f32x4{0.f, 0.f, 0.f, 0.f};

  auto stage_tile = [&](int kt2, uint32_t bufByte) {
    size_t kb = (size_t)kt2 * 128;
#pragma unroll
    for (int i = 0; i < 4; ++i)
      stage16(aSrc[i] + kb, (char*)LDS + bufByte + aDst[i]);
#pragma unroll
    for (int i = 0; i < 2; ++i)
      stage16(bSrc[i] + kb, (char*)LDS + bufByte + bDst[i]);
  };

  auto tile_body = [&](int kt, uint32_t cur, int mode) {
    bf16x8 aR[4][2], bR[4][2];
#pragma unroll
    for (int mi = 0; mi < 4; ++mi)
#pragma unroll
      for (int ks = 0; ks < 2; ++ks)
        aR[mi][ks] = *(const bf16x8*)((const char*)LDS + cur + aoff[mi][ks]);
#pragma unroll
    for (int ni = 0; ni < 4; ++ni)
#pragma unroll
      for (int ks = 0; ks < 2; ++ks)
        bR[ni][ks] = *(const bf16x8*)((const char*)LDS + cur + boff[ni][ks]);
    if (mode == 2) {
      uint32_t stg = cur + 2 * LDSB;
      if (stg >= 3 * LDSB) stg -= 3 * LDSB;
      stage_tile(kt + 2, stg);
    }
    __builtin_amdgcn_sched_barrier(0);
    __builtin_amdgcn_s_setprio(1);
#pragma unroll
    for (int ks = 0; ks < 2; ++ks)
#pragma unroll
      for (int mi = 0; mi < 4; ++mi)
#pragma unroll
        for (int ni = 0; ni < 4; ++ni)
          acc[mi][ni] = __builtin_amdgcn_mfma_f32_16x16x32_bf16(aR[mi][ks], bR[ni][ks], acc[mi][ni], 0, 0, 0);
    __builtin_amdgcn_s_setprio(0);
    if (mode == 2) {
      asm volatile("s_waitcnt vmcnt(6)" ::: "memory");
    } else if (mode == 1) {
      asm volatile("s_waitcnt vmcnt(0)" ::: "memory");
    }
    if (mode != 0) {
      __builtin_amdgcn_s_barrier();
      __builtin_amdgcn_sched_barrier(0);
    }
  };

  stage_tile(0, 0);
  stage_tile(1, LDSB);
  asm volatile("s_waitcnt vmcnt(6)" ::: "memory");
  __builtin_amdgcn_s_barrier();
  __builtin_amdgcn_sched_barrier(0);

  uint32_t cur = 0;
#pragma unroll 1
  for (int kt = 0; kt < NT - 2; ++kt) {
    tile_body(kt, cur, 2);
    cur += LDSB; if (cur == 3 * LDSB) cur = 0;
  }
  tile_body(NT - 2, cur, 1);
  cur += LDSB; if (cur == 3 * LDSB) cur = 0;
  tile_body(NT - 1, cur, 0);

  int bq = n0 >> 8;
#pragma unroll
  for (int mi = 0; mi < 4; ++mi) {
    int row = m0 + wm * 64 + mi * 16 + q * 4;
    float di[4];
#pragma unroll
    for (int rr = 0; rr < 4; ++rr) di[rr] = dinv[row + rr];
#pragma unroll
    for (int ni = 0; ni < 4; ++ni) {
      int col = n0 + wn * 64 + ni * 16 + r16;
      int o = col & 255;
#pragma unroll
      for (int rr = 0; rr < 4; ++rr) {
        size_t oi = ((size_t)bq * N_NODES + (row + rr)) * F_DIM + o;
        float u = bf2f(HWb[oi]) - di[rr] * acc[mi][ni][rr];
        Out[oi] = u > 0.f ? u : 0.f;
      }
    }
  }
}

extern "C" void kernel_launch(void* const* d_in, const int* in_sizes, int n_in,
                              void* d_out, int out_size, void* d_ws, size_t ws_size,
                              hipStream_t stream) {
  (void)in_sizes; (void)n_in; (void)out_size; (void)ws_size;
  const float* H = (const float*)d_in[0];
  const float* W = (const float*)d_in[1];
  const float* A = (const float*)d_in[2];
  float* out = (float*)d_out;

  char* ws = (char*)d_ws;
  size_t off = 0;
  auto alloc = [&](size_t bytes) {
    char* p = ws + off;
    off += (bytes + 255) & ~(size_t)255;
    return p;
  };
  float*          Dd   = (float*)alloc((size_t)N_NODES * 4);
  float*          dinv = (float*)alloc((size_t)N_NODES * 4);
  unsigned short* Sb   = (unsigned short*)alloc((size_t)N_NODES * N_NODES * 2);        // 32 MB
  unsigned short* HWb  = (unsigned short*)alloc((size_t)BATCH * N_NODES * F_DIM * 2);  // 16 MB
  unsigned short* Gt   = (unsigned short*)alloc((size_t)BATCH * F_DIM * N_NODES * 2);  // 16 MB
  unsigned short* Wt   = (unsigned short*)alloc((size_t)F_DIM * F_DIM * 2);
  unsigned short* Hb   = (unsigned short*)alloc((size_t)BATCH * N_NODES * F_DIM * 2);  // 16 MB

  hipMemsetAsync(Dd, 0, N_NODES * 4, stream);
  k_pre<<<dim3(64, 64), 256, 0, stream>>>(A, Sb, Dd, (const float4*)H, (ushort4*)Hb, W, Wt);
  k_dinv<<<16, 256, 0, stream>>>(Dd, dinv);
  k_gemm1<<<dim3(2, 256), 512, 0, stream>>>(Hb, Wt, dinv, HWb, Gt);
  k_gemm2<<<dim3(256), 512, 0, stream>>>(Sb, Gt, HWb, dinv, out);
}